// Round 2
// 571.769 us; speedup vs baseline: 1.0395x; 1.0395x over previous
//
#include <hip/hip_runtime.h>
#include <cstdint>

// SparseMLP: out = relu(relu(x@W1^T+b1)@W2^T+b2)@W3^T+b3
// M = N = K = 4096 per layer. fp32 in/out; fp16 MFMA internally.
//
// R6 == R5 resubmit (R5 bench died to container-infra failure; barrier/vmcnt
// ledger re-audited, no deadlock path found). Structure vs R4 (594us):
// replace the 128x128 2-barrier-per-K-step GEMM (m97-class, MfmaUtil 48%)
// with the 256x256 phase-interleaved counted-vmcnt schedule (T2+T3+T4+T5):
//  - 512 thr / 8 waves (2Mx4N), per-wave 128x64 out, acc[8][4].
//  - LDS 128KB: 2 buf x 4 regions {Ah0,Bh0,Bh1,Ah1} x (128 rows x 64 k) f16,
//    same XOR-chunk swizzle as R4 (slot s of row r holds chunk s^(r&7); 0
//    bank conflicts measured).
//  - 4 phases per K-tile, one quadrant (16 MFMA) + one half-tile stage per
//    phase; vmcnt(6) ONCE per tile placed BEFORE the tile-end barrier so
//    3 half-tiles stay in flight across barriers (never drains to 0 in the
//    main loop) and cross-wave glds->ds_read visibility is barrier-ordered.
//  - Region stage order (Ah1 of T+1 @p0; Ah0/Bh0/Bh1 of T+2 @p1..p3) makes
//    every LDS overwrite strictly barrier-after that region's last read.
//  - setprio(1) around MFMA clusters; lgkmcnt(0)+sched_barrier(0) per rule 18.
// Converts: single 4-tensor launch when ws >= 160MB, else R4's 3-launch path.

#define MATN 4096
#define NT (MATN / 64)  // 64 K-tiles

typedef _Float16 half8 __attribute__((ext_vector_type(8)));
typedef float f32x4 __attribute__((ext_vector_type(4)));

// async global->LDS, 16B/lane. LDS dest = wave-uniform base + lane*16.
__device__ __forceinline__ void glds16(const void* g, void* l) {
    __builtin_amdgcn_global_load_lds(
        (const __attribute__((address_space(1))) char*)(uintptr_t)g,
        (__attribute__((address_space(3))) char*)(uintptr_t)l,
        16, 0, 0);
}

__device__ __forceinline__ void cvt_body(const float* __restrict__ in,
                                         _Float16* __restrict__ out, int n8) {
    for (int g = blockIdx.x * 256 + threadIdx.x; g < n8; g += gridDim.x * 256) {
        size_t i = (size_t)g * 8;
        float4 a = *(const float4*)(in + i);
        float4 b = *(const float4*)(in + i + 4);
        half8 o;
        o[0] = (_Float16)a.x; o[1] = (_Float16)a.y;
        o[2] = (_Float16)a.z; o[3] = (_Float16)a.w;
        o[4] = (_Float16)b.x; o[5] = (_Float16)b.y;
        o[6] = (_Float16)b.z; o[7] = (_Float16)b.w;
        *(half8*)(out + i) = o;
    }
}

__global__ __launch_bounds__(256)
void cvt_f16(const float* __restrict__ in, _Float16* __restrict__ out, int n8) {
    cvt_body(in, out, n8);
}

__global__ __launch_bounds__(256)
void cvt_f16_2(const float* __restrict__ i0, _Float16* __restrict__ o0,
               const float* __restrict__ i1, _Float16* __restrict__ o1, int n8) {
    cvt_body(blockIdx.y ? i1 : i0, blockIdx.y ? o1 : o0, n8);
}

__global__ __launch_bounds__(256)
void cvt_f16_4(const float* __restrict__ i0, _Float16* __restrict__ o0,
               const float* __restrict__ i1, _Float16* __restrict__ o1,
               const float* __restrict__ i2, _Float16* __restrict__ o2,
               const float* __restrict__ i3, _Float16* __restrict__ o3, int n8) {
    const float* in;
    _Float16* out;
    switch (blockIdx.y) {
        case 0: in = i0; out = o0; break;
        case 1: in = i1; out = o1; break;
        case 2: in = i2; out = o2; break;
        default: in = i3; out = o3; break;
    }
    cvt_body(in, out, n8);
}

// C[m][n] = sum_k A[m][k]*B[n][k] + bias[n] (optional ReLU).
// A,B: [4096][4096] f16 row-major (K-contig). 256x256 tile, BK=64.
#define MFMA_(d, x, y) d = __builtin_amdgcn_mfma_f32_16x16x32_f16(x, y, d, 0, 0, 0)

template <bool RELU, typename OutT>
__global__ __launch_bounds__(512, 2)
void gemm_bt(const _Float16* __restrict__ A, const _Float16* __restrict__ B,
             const float* __restrict__ bias, OutT* __restrict__ C) {
    // [buf][region][128 rows x 64 k]; region: 0=Ah0 1=Bh0 2=Bh1 3=Ah1. 128 KB.
    __shared__ _Float16 lds[2][4][128 * 64];

    const int tid  = threadIdx.x;
    const int lane = tid & 63;
    const int w    = tid >> 6;   // 8 waves
    const int wm   = w >> 2;     // 0..1
    const int wn   = w & 3;      // 0..3
    const int l16  = lane & 15;
    const int kq   = lane >> 4;  // 0..3

    // bijective XCD swizzle: 256 blocks, 256 % 8 == 0
    const int bid   = blockIdx.y * 16 + blockIdx.x;
    const int sbid  = (bid & 7) * 32 + (bid >> 3);
    const int tileM = (sbid >> 4) * 256;
    const int tileN = (sbid & 15) * 256;

    // staging: thread t -> row rin (0..63), chunk gch = (t&7)^(rin&7); each
    // STAGE covers 128 rows x 64 k via 2 issues (rows rin, rin+64).
    const int rin = tid >> 3;
    const int gch = (tid & 7) ^ (rin & 7);
    char* const ldsb = (char*)lds;
    const int wq = w * 1024;  // wave-uniform LDS sub-base

    const _Float16* const arow = A + (size_t)(tileM + rin) * MATN + gch * 8;
    const _Float16* const brow = B + (size_t)(tileN + rin) * MATN + gch * 8;

#define STAGE(Tt, s, rowp, roff)                                               \
    do {                                                                       \
        if ((Tt) < NT) {                                                       \
            const _Float16* g_ = (rowp) + (size_t)(roff) * MATN + (Tt) * 64;   \
            char* l_ = ldsb + ((((Tt) & 1) * 4 + (s)) * 16384) + wq;           \
            glds16(g_, l_);                                                    \
            glds16(g_ + (size_t)64 * MATN, l_ + 8192);                         \
        }                                                                      \
    } while (0)

    // fragment read offsets: row = (frag base) + 16*wx + l16, row&7 == l16&7;
    // chunk (kh*4+kq) lives at slot (kh*4+kq)^(l16&7): 2-way/quarter-wave = free.
    const int rbA = (wm * 16 + l16) * 128;
    const int rbB = (wn * 16 + l16) * 128;
    const int ok0 = (kq ^ (l16 & 7)) * 16;
    const int ok1 = ok0 ^ 64;

    half8 a[4][2], b0[2][2], b1[2][2];
    f32x4 acc[8][4] = {};

    // prologue: tile0 {Ah0,Bh0,Bh1,Ah1} + tile1 {Ah0,Bh0,Bh1} = 14 loads
    STAGE(0, 0, arow, 0);
    STAGE(0, 1, brow, 0);
    STAGE(0, 2, brow, 128);
    STAGE(0, 3, arow, 128);
    STAGE(1, 0, arow, 0);
    STAGE(1, 1, brow, 0);
    STAGE(1, 2, brow, 128);
    asm volatile("s_waitcnt vmcnt(6)" ::: "memory");  // tile0 landed
    __builtin_amdgcn_s_barrier();

#pragma unroll 2
    for (int T = 0; T < NT; ++T) {
        const char* bufA0 = ldsb + ((T & 1) * 4 + 0) * 16384;
        const char* bufB0 = ldsb + ((T & 1) * 4 + 1) * 16384;
        const char* bufB1 = ldsb + ((T & 1) * 4 + 2) * 16384;
        const char* bufA1 = ldsb + ((T & 1) * 4 + 3) * 16384;

        // ---- phase 0: quadrant (mhalf0, nhalf0) ----
#pragma unroll
        for (int mi = 0; mi < 4; ++mi) {
            a[mi][0] = *(const half8*)(bufA0 + mi * 4096 + rbA + ok0);
            a[mi][1] = *(const half8*)(bufA0 + mi * 4096 + rbA + ok1);
        }
#pragma unroll
        for (int ni = 0; ni < 2; ++ni) {
            b0[ni][0] = *(const half8*)(bufB0 + ni * 8192 + rbB + ok0);
            b0[ni][1] = *(const half8*)(bufB0 + ni * 8192 + rbB + ok1);
        }
        STAGE(T + 1, 3, arow, 128);  // Ah1 of T+1 -> buf^1
        __builtin_amdgcn_s_barrier();
        asm volatile("s_waitcnt lgkmcnt(0)" ::: "memory");
        __builtin_amdgcn_sched_barrier(0);
        __builtin_amdgcn_s_setprio(1);
#pragma unroll
        for (int mi = 0; mi < 4; ++mi)
#pragma unroll
            for (int ni = 0; ni < 2; ++ni) {
                MFMA_(acc[mi][ni], a[mi][0], b0[ni][0]);
                MFMA_(acc[mi][ni], a[mi][1], b0[ni][1]);
            }
        __builtin_amdgcn_s_setprio(0);
        __builtin_amdgcn_s_barrier();

        // ---- phase 1: quadrant (0,1) ----
#pragma unroll
        for (int ni = 0; ni < 2; ++ni) {
            b1[ni][0] = *(const half8*)(bufB1 + ni * 8192 + rbB + ok0);
            b1[ni][1] = *(const half8*)(bufB1 + ni * 8192 + rbB + ok1);
        }
        STAGE(T + 2, 0, arow, 0);  // Ah0 of T+2 -> this buf (read @p0: safe)
        __builtin_amdgcn_s_barrier();
        asm volatile("s_waitcnt lgkmcnt(0)" ::: "memory");
        __builtin_amdgcn_sched_barrier(0);
        __builtin_amdgcn_s_setprio(1);
#pragma unroll
        for (int mi = 0; mi < 4; ++mi)
#pragma unroll
            for (int ni = 0; ni < 2; ++ni) {
                MFMA_(acc[mi][2 + ni], a[mi][0], b1[ni][0]);
                MFMA_(acc[mi][2 + ni], a[mi][1], b1[ni][1]);
            }
        __builtin_amdgcn_s_setprio(0);
        __builtin_amdgcn_s_barrier();

        // ---- phase 2: quadrant (1,1) ----
#pragma unroll
        for (int mi = 0; mi < 4; ++mi) {
            a[mi][0] = *(const half8*)(bufA1 + mi * 4096 + rbA + ok0);
            a[mi][1] = *(const half8*)(bufA1 + mi * 4096 + rbA + ok1);
        }
        STAGE(T + 2, 1, brow, 0);  // Bh0 of T+2 (read @p0: safe)
        __builtin_amdgcn_s_barrier();
        asm volatile("s_waitcnt lgkmcnt(0)" ::: "memory");
        __builtin_amdgcn_sched_barrier(0);
        __builtin_amdgcn_s_setprio(1);
#pragma unroll
        for (int mi = 0; mi < 4; ++mi)
#pragma unroll
            for (int ni = 0; ni < 2; ++ni) {
                MFMA_(acc[4 + mi][2 + ni], a[mi][0], b1[ni][0]);
                MFMA_(acc[4 + mi][2 + ni], a[mi][1], b1[ni][1]);
            }
        __builtin_amdgcn_s_setprio(0);
        __builtin_amdgcn_s_barrier();

        // ---- phase 3: quadrant (1,0) ---- (all operands already in regs)
        STAGE(T + 2, 2, brow, 128);  // Bh1 of T+2 (read @p1: safe)
        __builtin_amdgcn_s_barrier();
        __builtin_amdgcn_s_setprio(1);
#pragma unroll
        for (int mi = 0; mi < 4; ++mi)
#pragma unroll
            for (int ni = 0; ni < 2; ++ni) {
                MFMA_(acc[4 + mi][ni], a[mi][0], b0[ni][0]);
                MFMA_(acc[4 + mi][ni], a[mi][1], b0[ni][1]);
            }
        __builtin_amdgcn_s_setprio(0);
        // counted wait for NEXT tile, BEFORE the barrier: cross-wave safe,
        // leaves 3 half-tiles (6 loads) in flight. Last staged tile drains.
        if (T < NT - 2)
            asm volatile("s_waitcnt vmcnt(6)" ::: "memory");
        else if (T == NT - 2)
            asm volatile("s_waitcnt vmcnt(0)" ::: "memory");
        __builtin_amdgcn_s_barrier();
    }
#undef STAGE

    // epilogue: C/D layout col = lane&15, row = (lane>>4)*4 + reg (m89)
#pragma unroll
    for (int ni = 0; ni < 4; ++ni) {
        const int gn = tileN + ni * 64 + wn * 16 + l16;
        const float bv = bias[gn];
#pragma unroll
        for (int mi = 0; mi < 8; ++mi) {
            const int gm = tileM + mi * 32 + wm * 16 + kq * 4;
#pragma unroll
            for (int r = 0; r < 4; ++r) {
                float v = acc[mi][ni][r] + bv;
                if (RELU) v = v > 0.f ? v : 0.f;
                C[(size_t)(gm + r) * MATN + gn] = (OutT)v;
            }
        }
    }
}

extern "C" void kernel_launch(void* const* d_in, const int* in_sizes, int n_in,
                              void* d_out, int out_size, void* d_ws, size_t ws_size,
                              hipStream_t stream) {
    const float* x  = (const float*)d_in[0];
    const float* W1 = (const float*)d_in[1];
    const float* b1 = (const float*)d_in[2];
    const float* W2 = (const float*)d_in[3];
    const float* b2 = (const float*)d_in[4];
    const float* W3 = (const float*)d_in[5];
    const float* b3 = (const float*)d_in[6];
    float* out = (float*)d_out;

    const size_t MAT = (size_t)MATN * MATN;
    const size_t HB  = MAT * 2;  // bytes per f16 matrix
    const int n8 = (int)(MAT / 8);
    dim3 ggrid(MATN / 256, MATN / 256);  // 16x16

    if (ws_size >= HB * 5) {
        // roomy path: all converts in one launch
        _Float16* xb = (_Float16*)d_ws;
        _Float16* w1 = (_Float16*)((char*)d_ws + HB);
        _Float16* w2 = (_Float16*)((char*)d_ws + HB * 2);
        _Float16* w3 = (_Float16*)((char*)d_ws + HB * 3);
        _Float16* h1 = (_Float16*)((char*)d_ws + HB * 4);
        _Float16* h2 = xb;  // xb dead after layer 1

        cvt_f16_4<<<dim3(2048, 4), 256, 0, stream>>>(x, xb, W1, w1, W2, w2,
                                                     W3, w3, n8);
        gemm_bt<true, _Float16><<<ggrid, 512, 0, stream>>>(xb, w1, b1, h1);
        gemm_bt<true, _Float16><<<ggrid, 512, 0, stream>>>(h1, w2, b2, h2);
        gemm_bt<false, float><<<ggrid, 512, 0, stream>>>(h2, w3, b3, out);
    } else {
        // 96MB fallback: shared per-layer W buffer
        _Float16* xb = (_Float16*)d_ws;
        _Float16* wb = (_Float16*)((char*)d_ws + HB);
        _Float16* h1 = (_Float16*)((char*)d_ws + HB * 2);
        _Float16* h2 = xb;

        cvt_f16_2<<<dim3(2048, 2), 256, 0, stream>>>(x, xb, W1, wb, n8);
        gemm_bt<true, _Float16><<<ggrid, 512, 0, stream>>>(xb, wb, b1, h1);
        cvt_f16<<<2048, 256, 0, stream>>>(W2, wb, n8);
        gemm_bt<true, _Float16><<<ggrid, 512, 0, stream>>>(h1, wb, b2, h2);
        cvt_f16<<<2048, 256, 0, stream>>>(W3, wb, n8);
        gemm_bt<false, float><<<ggrid, 512, 0, stream>>>(h2, wb, b3, out);
    }
}